// Round 3
// baseline (3694.615 us; speedup 1.0000x reference)
//
#include <hip/hip_runtime.h>
#include <hip/hip_cooperative_groups.h>
#include <float.h>

namespace cg = cooperative_groups;

#define NLVL 12
#define NB 16
#define TPB 256

// meta layout (ints): [0..16) counts_f | [16..32) counts_b | [32..48) counts_o
// [48..64) cursor_f | [64..80) cursor_b | [80..96) cursor_o
// [96..109) base_f | [128..141) base_b | [160..177) base_o

struct Params {
    const int *nt, *ninv, *src, *dst, *fl, *bl, *batch;
    const float *We, *be, *Wf, *bf, *Wb, *bb;
    float *h, *agg, *out;
    int *rowptr, *cursor, *col, *nb_f, *nb_b, *onodes, *bsums, *meta;
    int N, E, M, outN;
};

__device__ inline void atomicMaxF(float* addr, float val) {
    int* ai = (int*)addr;
    int old = *ai;
    while (__int_as_float(old) < val) {
        int assumed = old;
        old = atomicCAS(ai, assumed, __float_as_int(val));
        if (old == assumed) break;
    }
}

__global__ __launch_bounds__(TPB, 4) void k_mega(Params p) {
    cg::grid_group grid = cg::this_grid();
    __shared__ float Ws[64 * 64];           // 16 KB weight stage
    __shared__ int   si[TPB];               // scan scratch
    __shared__ int   hf[NLVL], hb[NLVL], ho[NB];
    __shared__ int   basef[NLVL], baseb[NLVL], baseo[NB];

    const int tid = threadIdx.x, bid = blockIdx.x;
    const int G = gridDim.x;
    const int gtid = bid * TPB + tid, gs = G * TPB;
    const int lane = tid & 63;
    const int wid = gtid >> 6, nw = gs >> 6;
    const int N = p.N, E = p.E, M = p.M;

    // ---------- phase 0: zero counters, init out ----------
    for (int i = gtid; i < M + 1; i += gs) p.rowptr[i] = 0;
    for (int i = gtid; i < 48; i += gs) p.meta[i] = 0;
    for (int i = gtid; i < p.outN; i += gs)
        p.out[i] = ((i & 127) < 64) ? -FLT_MAX : 0.0f;   // max-pool init == finfo.min
    grid.sync();

    // ---------- phase 1: degree atomics + node hist + encoder ----------
    for (int e = gtid; e < E; e += gs) {
        atomicAdd(&p.rowptr[p.dst[e]], 1);       // in-deg
        atomicAdd(&p.rowptr[N + p.src[e]], 1);   // out-deg
    }
    if (tid < NLVL) { hf[tid] = 0; hb[tid] = 0; }
    if (tid < NB) ho[tid] = 0;
    __syncthreads();
    for (int i = gtid; i < N; i += gs) {
        atomicAdd(&hf[p.fl[i]], 1);
        atomicAdd(&hb[p.bl[i]], 1);
        if (p.nt[i] == 1) atomicAdd(&ho[p.batch[i]], 1);
    }
    __syncthreads();
    if (tid < NLVL) { atomicAdd(&p.meta[tid], hf[tid]); atomicAdd(&p.meta[16 + tid], hb[tid]); }
    if (tid < NB) atomicAdd(&p.meta[32 + tid], ho[tid]);
    // encoder: h = [nt, ninv] @ W_enc + b_enc
    for (int t = gtid; t < N * 16; t += gs) {
        int v = t >> 4;
        int j = (t & 15) * 4;
        float a = (float)p.nt[v], c = (float)p.ninv[v];
        float4 w0 = *(const float4*)(p.We + j);
        float4 w1 = *(const float4*)(p.We + 64 + j);
        float4 b  = *(const float4*)(p.be + j);
        float4 r;
        r.x = fmaf(a, w0.x, fmaf(c, w1.x, b.x));
        r.y = fmaf(a, w0.y, fmaf(c, w1.y, b.y));
        r.z = fmaf(a, w0.z, fmaf(c, w1.z, b.z));
        r.w = fmaf(a, w0.w, fmaf(c, w1.w, b.w));
        *(float4*)(p.h + (size_t)v * 64 + j) = r;
    }
    grid.sync();

    // ---------- phase 2a: per-block chunk totals of rowptr[0..M) ----------
    const int chunk = (M + G - 1) / G;
    const int per = (chunk + TPB - 1) / TPB;
    const int c0 = bid * chunk;
    int tsum = 0;
    for (int k = 0; k < per; k++) {
        int idx = c0 + tid * per + k;
        if (idx < c0 + chunk && idx < M) tsum += p.rowptr[idx];
    }
    si[tid] = tsum;
    __syncthreads();
    for (int off = 128; off > 0; off >>= 1) {
        if (tid < off) si[tid] += si[tid + off];
        __syncthreads();
    }
    if (tid == 0) p.bsums[bid] = si[0];
    grid.sync();

    // ---------- phase 2b: block 0 scans bsums; block 1 scans meta ----------
    if (bid == 0) {
        int v0[4];
        int ssum = 0;
        for (int k = 0; k < 4; k++) {
            int idx = tid * 4 + k;
            v0[k] = (idx < G) ? p.bsums[idx] : 0;
            ssum += v0[k];
        }
        si[tid] = ssum;
        __syncthreads();
        for (int off = 1; off < TPB; off <<= 1) {
            int a = (tid >= off) ? si[tid - off] : 0;
            __syncthreads();
            si[tid] += a;
            __syncthreads();
        }
        int run = si[tid] - ssum;   // exclusive
        for (int k = 0; k < 4; k++) {
            int idx = tid * 4 + k;
            if (idx < G) { int t = v0[k]; p.bsums[idx] = run; run += t; }
        }
    } else if (bid == 1) {
        if (tid == 0) { int s = 0; for (int l = 0; l < NLVL; l++) { p.meta[96 + l] = s; p.meta[48 + l] = s; s += p.meta[l]; } p.meta[96 + NLVL] = s; }
        if (tid == 1) { int s = 0; for (int l = 0; l < NLVL; l++) { p.meta[128 + l] = s; p.meta[64 + l] = s; s += p.meta[16 + l]; } p.meta[128 + NLVL] = s; }
        if (tid == 2) { int s = 0; for (int b = 0; b < NB; b++) { p.meta[160 + b] = s; p.meta[80 + b] = s; s += p.meta[32 + b]; } p.meta[160 + NB] = s; }
    }
    grid.sync();

    // ---------- phase 2c: finalize rowptr/cursor ----------
    {
        int off0 = p.bsums[bid];
        si[tid] = tsum;
        __syncthreads();
        for (int off = 1; off < TPB; off <<= 1) {
            int a = (tid >= off) ? si[tid - off] : 0;
            __syncthreads();
            si[tid] += a;
            __syncthreads();
        }
        int run = off0 + si[tid] - tsum;    // exclusive prefix for this thread
        for (int k = 0; k < per; k++) {
            int idx = c0 + tid * per + k;
            if (idx < c0 + chunk && idx < M) {
                int c = p.rowptr[idx];
                p.rowptr[idx] = run;
                p.cursor[idx] = run;
                run += c;
            }
        }
        if (gtid == 0) p.rowptr[M] = 2 * E;
    }
    grid.sync();

    // ---------- phase 3: CSR fill + node scatter ----------
    for (int e = gtid; e < E; e += gs) {
        int s = p.src[e], d = p.dst[e];
        p.col[atomicAdd(&p.cursor[d], 1)] = s;        // in-edges: other = src
        p.col[atomicAdd(&p.cursor[N + s], 1)] = d;    // out-edges: other = dst
    }
    for (int i0 = bid * TPB; i0 < N; i0 += gs) {
        int i = i0 + tid;
        bool valid = (i < N);
        if (tid < NLVL) { hf[tid] = 0; hb[tid] = 0; }
        if (tid < NB) ho[tid] = 0;
        __syncthreads();
        int lf = 0, lb = 0, ob = -1;
        if (valid) {
            lf = p.fl[i]; lb = p.bl[i];
            atomicAdd(&hf[lf], 1);
            atomicAdd(&hb[lb], 1);
            if (p.nt[i] == 1) { ob = p.batch[i]; atomicAdd(&ho[ob], 1); }
        }
        __syncthreads();
        if (tid < NLVL) {
            basef[tid] = atomicAdd(&p.meta[48 + tid], hf[tid]);
            baseb[tid] = atomicAdd(&p.meta[64 + tid], hb[tid]);
            hf[tid] = 0; hb[tid] = 0;
        }
        if (tid < NB) {
            baseo[tid] = atomicAdd(&p.meta[80 + tid], ho[tid]);
            ho[tid] = 0;
        }
        __syncthreads();
        if (valid) {
            p.nb_f[basef[lf] + atomicAdd(&hf[lf], 1)] = i;
            p.nb_b[baseb[lb] + atomicAdd(&hb[lb], 1)] = i;
            if (ob >= 0) p.onodes[baseo[ob] + atomicAdd(&ho[ob], 1)] = i;
        }
        __syncthreads();
    }
    grid.sync();

    // ---------- sweeps ----------
    const int q = lane >> 4;            // quarter-wave id
    const int fb = (lane & 15) * 4;     // feature base for float4
    for (int dir = 0; dir < 2; dir++) {
        const int* nb     = dir ? p.nb_b : p.nb_f;
        const int* base   = p.meta + (dir ? 128 : 96);
        const int* rp     = p.rowptr + (dir ? N : 0);
        const float* W    = dir ? p.Wb : p.Wf;
        const float* bias = dir ? p.bb : p.bf;
        for (int j = tid; j < 4096; j += TPB) Ws[j] = W[j];   // stage once per dir
        __syncthreads();
        float bv = bias[lane];
        for (int l = 1; l < NLVL; l++) {
            int start = base[l], cnt = base[l + 1] - start;
            // agg phase: quarter-wave float4 gathers (4 neighbors/iteration)
            for (int i = wid; i < cnt; i += nw) {
                int v = nb[start + i];
                int rpv = rp[v], rpe = rp[v + 1];
                float4 acc = make_float4(0.f, 0.f, 0.f, 0.f);
                for (int cb = rpv + q; cb < rpe; cb += 4) {
                    int u = p.col[cb];                                  // broadcast within quarter
                    const float4 x = *(const float4*)(p.h + (size_t)u * 64 + fb);
                    acc.x += x.x; acc.y += x.y; acc.z += x.z; acc.w += x.w;
                }
                acc.x += __shfl_xor(acc.x, 16, 64); acc.y += __shfl_xor(acc.y, 16, 64);
                acc.z += __shfl_xor(acc.z, 16, 64); acc.w += __shfl_xor(acc.w, 16, 64);
                acc.x += __shfl_xor(acc.x, 32, 64); acc.y += __shfl_xor(acc.y, 32, 64);
                acc.z += __shfl_xor(acc.z, 32, 64); acc.w += __shfl_xor(acc.w, 32, 64);
                if (q == 0) *(float4*)(p.agg + (size_t)i * 64 + fb) = acc;
            }
            grid.sync();
            // matmul phase: h[v] = agg @ W + deg * bias
            for (int i = wid; i < cnt; i += nw) {
                int v = nb[start + i];
                int deg = rp[v + 1] - rp[v];
                float a = p.agg[(size_t)i * 64 + lane];
                float o = bv * (float)deg;
                #pragma unroll
                for (int k = 0; k < 64; k++)
                    o = fmaf(__shfl(a, k, 64), Ws[k * 64 + lane], o);
                p.h[(size_t)v * 64 + lane] = o;
            }
            grid.sync();
        }
    }

    // ---------- readout ----------
    const int S = nw / NB;              // slices per batch
    int b = wid / S;
    int sl = wid % S;
    if (b < NB) {
        int a0 = p.meta[160 + b], a1 = p.meta[160 + b + 1];
        int cnt = a1 - a0;
        if (cnt > 0) {
            int lo = a0 + (int)((long long)cnt * sl / S);
            int hi = a0 + (int)((long long)cnt * (sl + 1) / S);
            if (hi > lo) {
                float mx = -FLT_MAX, sm = 0.f;
                for (int k = lo; k < hi; k += 64) {
                    int take = hi - k; if (take > 64) take = 64;
                    int idl = (lane < take) ? p.onodes[k + lane] : 0;
                    for (int j = 0; j < take; j++) {
                        int v = __shfl(idl, j, 64);
                        float x = p.h[(size_t)v * 64 + lane];
                        mx = fmaxf(mx, x);
                        sm += x;
                    }
                }
                atomicMaxF(&p.out[b * 128 + lane], mx);
                atomicAdd(&p.out[b * 128 + 64 + lane], sm);
            }
        }
    }
}

extern "C" void kernel_launch(void* const* d_in, const int* in_sizes, int n_in,
                              void* d_out, int out_size, void* d_ws, size_t ws_size,
                              hipStream_t stream) {
    int N = in_sizes[0];
    int E = in_sizes[2] / 2;
    int M = 2 * N;

    Params p;
    p.nt    = (const int*)d_in[0];
    p.ninv  = (const int*)d_in[1];
    p.src   = (const int*)d_in[2];
    p.dst   = (const int*)d_in[2] + E;
    p.fl    = (const int*)d_in[3];
    p.bl    = (const int*)d_in[4];
    p.batch = (const int*)d_in[5];
    p.We    = (const float*)d_in[6];
    p.be    = (const float*)d_in[7];
    p.Wf    = (const float*)d_in[8];
    p.bf    = (const float*)d_in[9];
    p.Wb    = (const float*)d_in[10];
    p.bb    = (const float*)d_in[11];
    p.out   = (float*)d_out;
    p.N = N; p.E = E; p.M = M; p.outN = out_size;

    char* ws = (char*)d_ws;
    size_t off = 0;
    auto alloc = [&](size_t bytes) -> char* {
        char* q = ws + off;
        off = (off + bytes + 255) & ~(size_t)255;
        return q;
    };
    p.h      = (float*)alloc((size_t)N * 64 * sizeof(float));
    p.agg    = (float*)alloc((size_t)N * 64 * sizeof(float));
    p.rowptr = (int*)  alloc((size_t)(M + 1) * sizeof(int));
    p.cursor = (int*)  alloc((size_t)M * sizeof(int));
    p.col    = (int*)  alloc((size_t)2 * E * sizeof(int));
    p.nb_f   = (int*)  alloc((size_t)N * sizeof(int));
    p.nb_b   = (int*)  alloc((size_t)N * sizeof(int));
    p.onodes = (int*)  alloc((size_t)N * sizeof(int));
    p.bsums  = (int*)  alloc(1024 * sizeof(int));
    p.meta   = (int*)  alloc(256 * sizeof(int));

    // grid sized for guaranteed co-residency (cooperative launch requirement)
    int maxBlocksPerCU = 0;
    hipOccupancyMaxActiveBlocksPerMultiprocessor(&maxBlocksPerCU, k_mega, TPB, 0);
    if (maxBlocksPerCU < 1) maxBlocksPerCU = 1;
    int G = maxBlocksPerCU * 256;       // 256 CUs on MI355X
    if (G > 1024) G = 1024;             // bsums / scan-top capacity

    void* args[] = { &p };
    hipLaunchCooperativeKernel(k_mega, dim3(G), dim3(TPB), args, 0, stream);
}

// Round 4
// 1284.865 us; speedup vs baseline: 2.8755x; 2.8755x over previous
//
#include <hip/hip_runtime.h>
#include <float.h>

#define NLVL 12
#define NB 16
#define TPB 256

// meta layout (ints): [0..16) counts_f | [16..32) counts_b | [32..48) counts_o
// [48..64) cursor_f | [64..80) cursor_b | [80..96) cursor_o
// [96..109) base_f | [128..141) base_b | [160..177) base_o

// ---------------- setup: zero rowptr/meta, init out ----------------
__global__ void k_setup0(int* __restrict__ rowptr, int M, int* __restrict__ meta,
                         float* __restrict__ out, int outN) {
    int g = blockIdx.x * blockDim.x + threadIdx.x, gs = gridDim.x * blockDim.x;
    for (int i = g; i < M + 1; i += gs) rowptr[i] = 0;
    for (int i = g; i < 48; i += gs) meta[i] = 0;
    for (int i = g; i < outN; i += gs)
        out[i] = ((i & 127) < 64) ? -FLT_MAX : 0.0f;   // max-pool init == finfo.min
}

// ---------------- degrees + level/output histograms ----------------
__global__ void k_deg_hist(const int* __restrict__ src, const int* __restrict__ dst, int E, int N,
                           int* __restrict__ rowptr,
                           const int* __restrict__ fl, const int* __restrict__ bl,
                           const int* __restrict__ nt, const int* __restrict__ batch,
                           int* __restrict__ meta) {
    __shared__ int hf[NLVL], hb[NLVL], ho[NB];
    if (threadIdx.x < NLVL) { hf[threadIdx.x] = 0; hb[threadIdx.x] = 0; }
    if (threadIdx.x < NB) ho[threadIdx.x] = 0;
    __syncthreads();
    int g = blockIdx.x * blockDim.x + threadIdx.x, gs = gridDim.x * blockDim.x;
    for (int e = g; e < E; e += gs) {
        atomicAdd(&rowptr[dst[e]], 1);       // in-deg
        atomicAdd(&rowptr[N + src[e]], 1);   // out-deg
    }
    for (int i = g; i < N; i += gs) {
        atomicAdd(&hf[fl[i]], 1);
        atomicAdd(&hb[bl[i]], 1);
        if (nt[i] == 1) atomicAdd(&ho[batch[i]], 1);
    }
    __syncthreads();
    if (threadIdx.x < NLVL) { atomicAdd(&meta[threadIdx.x], hf[threadIdx.x]); atomicAdd(&meta[16 + threadIdx.x], hb[threadIdx.x]); }
    if (threadIdx.x < NB) atomicAdd(&meta[32 + threadIdx.x], ho[threadIdx.x]);
}

// ---------------- 3-kernel exclusive scan over M=2N (in place) ----------------
__global__ void k_scan1(int* __restrict__ data, int M, int* __restrict__ bsums) {
    __shared__ int s[512];
    int t = threadIdx.x;
    int g = blockIdx.x * 512 + t;
    int v = (g < M) ? data[g] : 0;
    s[t] = v;
    __syncthreads();
    for (int off = 1; off < 512; off <<= 1) {
        int add = (t >= off) ? s[t - off] : 0;
        __syncthreads();
        s[t] += add;
        __syncthreads();
    }
    if (g < M) data[g] = s[t] - v;
    if (t == 511) bsums[blockIdx.x] = s[511];
}

__global__ void k_scan_top(int* __restrict__ bsums, int nblk, int* __restrict__ meta) {
    __shared__ int s[1024];
    int t = threadIdx.x;
    // tiny meta scans (levels + output-node batches)
    if (t == 0) { int a = 0; for (int l = 0; l < NLVL; l++) { meta[96 + l] = a; meta[48 + l] = a; a += meta[l]; } meta[96 + NLVL] = a; }
    if (t == 1) { int a = 0; for (int l = 0; l < NLVL; l++) { meta[128 + l] = a; meta[64 + l] = a; a += meta[16 + l]; } meta[128 + NLVL] = a; }
    if (t == 2) { int a = 0; for (int b = 0; b < NB; b++) { meta[160 + b] = a; meta[80 + b] = a; a += meta[32 + b]; } meta[160 + NB] = a; }
    int v = (t < nblk) ? bsums[t] : 0;
    s[t] = v;
    __syncthreads();
    for (int off = 1; off < 1024; off <<= 1) {
        int add = (t >= off) ? s[t - off] : 0;
        __syncthreads();
        s[t] += add;
        __syncthreads();
    }
    if (t < nblk) bsums[t] = s[t] - v;
}

__global__ void k_scan_add(int* __restrict__ rowptr, int* __restrict__ cursor, int M, int total,
                           const int* __restrict__ bsums) {
    int g = blockIdx.x * blockDim.x + threadIdx.x;
    if (g >= M) return;
    int r = rowptr[g] + bsums[g >> 9];
    rowptr[g] = r;
    cursor[g] = r;
    if (g == 0) rowptr[M] = total;
}

// ---------------- fused: CSR fill + node scatter + encoder ----------------
__global__ void k_fill(const int* __restrict__ src, const int* __restrict__ dst, int E, int N,
                       int* __restrict__ cursor, int* __restrict__ col,
                       const int* __restrict__ fl, const int* __restrict__ bl,
                       const int* __restrict__ nt, const int* __restrict__ batch,
                       int* __restrict__ meta,
                       int* __restrict__ nb_f, int* __restrict__ nb_b, int* __restrict__ onodes,
                       const int* __restrict__ ninv,
                       const float* __restrict__ We, const float* __restrict__ be,
                       float* __restrict__ h) {
    __shared__ int hf[NLVL], hb[NLVL], ho[NB], basef[NLVL], baseb[NLVL], baseo[NB];
    int g = blockIdx.x * blockDim.x + threadIdx.x, gs = gridDim.x * blockDim.x;
    int tid = threadIdx.x;

    // CSR fill
    for (int e = g; e < E; e += gs) {
        int s = src[e], d = dst[e];
        col[atomicAdd(&cursor[d], 1)] = s;        // in-edges: other = src
        col[atomicAdd(&cursor[N + s], 1)] = d;    // out-edges: other = dst
    }

    // node scatter (block-chunked, uniform trip count)
    for (int i0 = blockIdx.x * TPB; i0 < N; i0 += gs) {
        int i = i0 + tid;
        bool valid = (i < N);
        if (tid < NLVL) { hf[tid] = 0; hb[tid] = 0; }
        if (tid < NB) ho[tid] = 0;
        __syncthreads();
        int lf = 0, lb = 0, ob = -1;
        if (valid) {
            lf = fl[i]; lb = bl[i];
            atomicAdd(&hf[lf], 1);
            atomicAdd(&hb[lb], 1);
            if (nt[i] == 1) { ob = batch[i]; atomicAdd(&ho[ob], 1); }
        }
        __syncthreads();
        if (tid < NLVL) {
            basef[tid] = atomicAdd(&meta[48 + tid], hf[tid]);
            baseb[tid] = atomicAdd(&meta[64 + tid], hb[tid]);
            hf[tid] = 0; hb[tid] = 0;
        }
        if (tid < NB) {
            baseo[tid] = atomicAdd(&meta[80 + tid], ho[tid]);
            ho[tid] = 0;
        }
        __syncthreads();
        if (valid) {
            nb_f[basef[lf] + atomicAdd(&hf[lf], 1)] = i;
            nb_b[baseb[lb] + atomicAdd(&hb[lb], 1)] = i;
            if (ob >= 0) onodes[baseo[ob] + atomicAdd(&ho[ob], 1)] = i;
        }
        __syncthreads();
    }

    // encoder: h = [nt, ninv] @ W_enc + b_enc
    for (int t = g; t < N * 16; t += gs) {
        int v = t >> 4;
        int j = (t & 15) * 4;
        float a = (float)nt[v], c = (float)ninv[v];
        float4 w0 = *(const float4*)(We + j);
        float4 w1 = *(const float4*)(We + 64 + j);
        float4 b  = *(const float4*)(be + j);
        float4 r;
        r.x = fmaf(a, w0.x, fmaf(c, w1.x, b.x));
        r.y = fmaf(a, w0.y, fmaf(c, w1.y, b.y));
        r.z = fmaf(a, w0.z, fmaf(c, w1.z, b.z));
        r.w = fmaf(a, w0.w, fmaf(c, w1.w, b.w));
        *(float4*)(h + (size_t)v * 64 + j) = r;
    }
}

// ---------------- fused per-level sweep: gather + matvec ----------------
// Buffer parity scheme (race-free same-level edges):
//   forward (dir=0): reads h/hN with pred (0<fl[u]<l), writes hN[v] always.
//   backward(dir=1): reads with pred ((fl[u]>0) != (0<bl[u]<l)) ? hN : h,
//                    writes (fl[v]>0 ? h : hN)  -- the dead slot.
__global__ void k_sweep(float* __restrict__ h, float* __restrict__ hN,
                        const int* __restrict__ nb, const int* __restrict__ base, int lvl,
                        const int* __restrict__ rp, const int* __restrict__ col,
                        const int* __restrict__ fl, const int* __restrict__ bl,
                        const float* __restrict__ W, const float* __restrict__ bias, int dir) {
    __shared__ float Ws[64 * 64];
    for (int i = threadIdx.x; i < 64 * 64; i += blockDim.x) Ws[i] = W[i];
    __syncthreads();
    int start = base[lvl], cnt = base[lvl + 1] - start;
    int lane   = threadIdx.x & 63;
    int wid    = (blockIdx.x * blockDim.x + threadIdx.x) >> 6;
    int nw     = (gridDim.x * blockDim.x) >> 6;
    const int q  = lane >> 4;           // quarter-wave id
    const int fb = (lane & 15) * 4;     // float4 feature base
    float bv = bias[lane];
    for (int i = wid; i < cnt; i += nw) {
        int v = nb[start + i];
        int rpv = rp[v], rpe = rp[v + 1];
        int deg = rpe - rpv;
        float4 acc = make_float4(0.f, 0.f, 0.f, 0.f);
        for (int cb = rpv + q; cb < rpe; cb += 4) {
            int u = col[cb];                    // broadcast within quarter
            bool useN;
            if (dir == 0) {
                int flu = fl[u];
                useN = (flu > 0) && (flu < lvl);
            } else {
                int flu = fl[u], blu = bl[u];
                bool updated = (blu > 0) && (blu < lvl);
                useN = ((flu > 0) != updated);
            }
            const float* srcb = useN ? hN : h;
            const float4 x = *(const float4*)(srcb + (size_t)u * 64 + fb);
            acc.x += x.x; acc.y += x.y; acc.z += x.z; acc.w += x.w;
        }
        acc.x += __shfl_xor(acc.x, 16, 64); acc.y += __shfl_xor(acc.y, 16, 64);
        acc.z += __shfl_xor(acc.z, 16, 64); acc.w += __shfl_xor(acc.w, 16, 64);
        acc.x += __shfl_xor(acc.x, 32, 64); acc.y += __shfl_xor(acc.y, 32, 64);
        acc.z += __shfl_xor(acc.z, 32, 64); acc.w += __shfl_xor(acc.w, 32, 64);
        // every lane now holds full row as float4: lane&15 -> a[4*(lane&15)..+3]
        float o = bv * (float)deg;
        #pragma unroll
        for (int j = 0; j < 16; j++) {
            float ax = __shfl(acc.x, j, 64);
            float ay = __shfl(acc.y, j, 64);
            float az = __shfl(acc.z, j, 64);
            float aw = __shfl(acc.w, j, 64);
            o = fmaf(ax, Ws[(4 * j + 0) * 64 + lane], o);
            o = fmaf(ay, Ws[(4 * j + 1) * 64 + lane], o);
            o = fmaf(az, Ws[(4 * j + 2) * 64 + lane], o);
            o = fmaf(aw, Ws[(4 * j + 3) * 64 + lane], o);
        }
        float* dstb = (dir == 0) ? hN : ((fl[v] > 0) ? h : hN);
        dstb[(size_t)v * 64 + lane] = o;
    }
}

// ---------------- readout ----------------
__device__ inline void atomicMaxF(float* addr, float val) {
    int* ai = (int*)addr;
    int old = *ai;
    while (__int_as_float(old) < val) {
        int assumed = old;
        old = atomicCAS(ai, assumed, __float_as_int(val));
        if (old == assumed) break;
    }
}

__global__ void k_readout(const float* __restrict__ h, const float* __restrict__ hN,
                          const int* __restrict__ fl, const int* __restrict__ bl,
                          const int* __restrict__ onodes,
                          const int* __restrict__ base_o, float* __restrict__ out) {
    int b = blockIdx.x >> 5;          // batch
    int sl = blockIdx.x & 31;         // slice
    int a0 = base_o[b], a1 = base_o[b + 1];
    int cnt = a1 - a0;
    if (cnt == 0) return;
    int lo = a0 + (int)((long long)cnt * sl / 32);
    int hi = a0 + (int)((long long)cnt * (sl + 1) / 32);
    int wcnt = hi - lo;
    int wave = threadIdx.x >> 6, lane = threadIdx.x & 63;
    int wl = lo + (wcnt * wave) / 4;
    int wh = lo + (wcnt * (wave + 1)) / 4;
    if (wh <= wl) return;
    float mx = -FLT_MAX, sm = 0.f;
    for (int k = wl; k < wh; k += 64) {
        int take = wh - k; if (take > 64) take = 64;
        int idl = 0, predl = 0;
        if (lane < take) {
            idl = onodes[k + lane];
            predl = ((fl[idl] > 0) != (bl[idl] > 0)) ? 1 : 0;  // final value in hN?
        }
        for (int j = 0; j < take; j++) {
            int v = __shfl(idl, j, 64);
            int pr = __shfl(predl, j, 64);
            const float* srcb = pr ? hN : h;
            float x = srcb[(size_t)v * 64 + lane];
            mx = fmaxf(mx, x);
            sm += x;
        }
    }
    atomicMaxF(&out[b * 128 + lane], mx);
    atomicAdd(&out[b * 128 + 64 + lane], sm);
}

extern "C" void kernel_launch(void* const* d_in, const int* in_sizes, int n_in,
                              void* d_out, int out_size, void* d_ws, size_t ws_size,
                              hipStream_t stream) {
    const int*   node_type = (const int*)d_in[0];
    const int*   ninv      = (const int*)d_in[1];
    const int*   edge_idx  = (const int*)d_in[2];
    const int*   fl        = (const int*)d_in[3];
    const int*   bl        = (const int*)d_in[4];
    const int*   batch     = (const int*)d_in[5];
    const float* W_enc     = (const float*)d_in[6];
    const float* b_enc     = (const float*)d_in[7];
    const float* W_f       = (const float*)d_in[8];
    const float* b_f       = (const float*)d_in[9];
    const float* W_b       = (const float*)d_in[10];
    const float* b_b       = (const float*)d_in[11];

    int N = in_sizes[0];
    int E = in_sizes[2] / 2;
    int M = 2 * N;
    const int* src = edge_idx;
    const int* dst = edge_idx + E;
    float* out = (float*)d_out;

    char* ws = (char*)d_ws;
    size_t off = 0;
    auto alloc = [&](size_t bytes) -> char* {
        char* p = ws + off;
        off = (off + bytes + 255) & ~(size_t)255;
        return p;
    };
    float* h      = (float*)alloc((size_t)N * 64 * sizeof(float));
    float* hN     = (float*)alloc((size_t)N * 64 * sizeof(float));
    int*   rowptr = (int*)  alloc((size_t)(M + 1) * sizeof(int));
    int*   cursor = (int*)  alloc((size_t)M * sizeof(int));
    int*   col    = (int*)  alloc((size_t)2 * E * sizeof(int));
    int*   nb_f   = (int*)  alloc((size_t)N * sizeof(int));
    int*   nb_b   = (int*)  alloc((size_t)N * sizeof(int));
    int*   onodes = (int*)  alloc((size_t)N * sizeof(int));
    int*   bsums  = (int*)  alloc(1024 * sizeof(int));
    int*   meta   = (int*)  alloc(256 * sizeof(int));
    int* base_f = meta + 96;
    int* base_b = meta + 128;
    int* base_o = meta + 160;

    int nscan = (M + 511) / 512;         // must be <= 1024

    k_setup0<<<512, 256, 0, stream>>>(rowptr, M, meta, out, out_size);
    k_deg_hist<<<512, 256, 0, stream>>>(src, dst, E, N, rowptr, fl, bl, node_type, batch, meta);
    k_scan1<<<nscan, 512, 0, stream>>>(rowptr, M, bsums);
    k_scan_top<<<1, 1024, 0, stream>>>(bsums, nscan, meta);
    k_scan_add<<<(M + 255) / 256, 256, 0, stream>>>(rowptr, cursor, M, 2 * E, bsums);
    k_fill<<<1024, 256, 0, stream>>>(src, dst, E, N, cursor, col, fl, bl, node_type, batch,
                                     meta, nb_f, nb_b, onodes, ninv, W_enc, b_enc, h);

    // forward sweep (one fused kernel per level)
    for (int l = 1; l < NLVL; l++)
        k_sweep<<<512, 256, 0, stream>>>(h, hN, nb_f, base_f, l, rowptr, col, fl, bl, W_f, b_f, 0);
    // backward sweep
    for (int l = 1; l < NLVL; l++)
        k_sweep<<<512, 256, 0, stream>>>(h, hN, nb_b, base_b, l, rowptr + N, col, fl, bl, W_b, b_b, 1);

    k_readout<<<NB * 32, 256, 0, stream>>>(h, hN, fl, bl, onodes, base_o, out);
}